// Round 7
// baseline (373.715 us; speedup 1.0000x reference)
//
#include <hip/hip_runtime.h>
#include <hip/hip_bf16.h>

#define SEQ 2048
#define BSZ 2
#define DIM 1024
#define NH 16
#define HD 64
#define WIN 8
#define PN 256

typedef __hip_bfloat16 bf16;
typedef __attribute__((ext_vector_type(8))) short short8;
typedef __attribute__((ext_vector_type(4))) short short4v;
typedef __attribute__((ext_vector_type(2))) unsigned int uint2v;
typedef __attribute__((ext_vector_type(4))) float f32x4;

__device__ __forceinline__ float b2f(bf16 x) { return __bfloat162float(x); }
__device__ __forceinline__ bf16 f2b(float x) { return __float2bfloat16(x); }
__device__ __forceinline__ short fbits(float x) { bf16 h = __float2bfloat16(x); return *(short*)&h; }

// pack two f32 -> two bf16 in one dword: round-half-up (+0x8000) then take the
// high halves via one v_perm_b32.  Differs from RNE only on exact ties.
__device__ __forceinline__ unsigned pk2bf(float lo, float hi) {
    return __builtin_amdgcn_perm(__float_as_uint(hi) + 0x8000u,
                                 __float_as_uint(lo) + 0x8000u, 0x07060302u);
}

// async global->LDS, 16B per lane; LDS dest must be wave-uniform base + lane*16
__device__ __forceinline__ void gl_lds16(const bf16* g, bf16* l) {
    __builtin_amdgcn_global_load_lds((const __attribute__((address_space(1))) void*)g,
                                     (__attribute__((address_space(3))) void*)l, 16, 0, 0);
}

// XOR-swizzled LDS addressing: 128B rows, byte ^= ((row&7)<<4).
__device__ __forceinline__ bf16* swzp(bf16* base, int row, int byteoff) {
    return (bf16*)((char*)base + (row << 7) + (byteoff ^ ((row & 7) << 4)));
}

// ---------------------------------------------------------------------------
// fp32 -> bf16 pre-convert: query (4M) + 6 weights (6M) + bias pack (6K fp32)
// ---------------------------------------------------------------------------
__global__ void convert_kernel(const float* __restrict__ q,
                               const float* __restrict__ w0, const float* __restrict__ w1,
                               const float* __restrict__ w2, const float* __restrict__ w3,
                               const float* __restrict__ w4, const float* __restrict__ w5,
                               const float* __restrict__ b0, const float* __restrict__ b1,
                               const float* __restrict__ b2, const float* __restrict__ b3,
                               const float* __restrict__ b4, const float* __restrict__ b5,
                               bf16* __restrict__ qbf, bf16* __restrict__ wbf,
                               float* __restrict__ bp) {
    int i = blockIdx.x * 256 + threadIdx.x;          // vector idx, 8 floats each
    const int QV = (SEQ * BSZ * DIM) / 8;            // 524288
    const int WV = (DIM * DIM) / 8;                  // 131072
    const int TV = QV + 6 * WV;
    if (i >= TV) {                                   // bias path: 768 chunks
        int j = i - TV;
        if (j >= 768) return;
        int mat = j >> 7, k = (j & 127) * 8;
        const float* s = (mat == 0) ? b0 : (mat == 1) ? b1 : (mat == 2) ? b2
                       : (mat == 3) ? b3 : (mat == 4) ? b4 : b5;
        *(f32x4*)(bp + mat * DIM + k)     = *(const f32x4*)(s + k);
        *(f32x4*)(bp + mat * DIM + k + 4) = *(const f32x4*)(s + k + 4);
        return;
    }
    const float* src;
    bf16* dst;
    size_t off;
    if (i < QV) { src = q; dst = qbf; off = (size_t)i * 8; }
    else {
        int j = i - QV;
        int mat = j / WV, k = j - mat * WV;
        src = (mat == 0) ? w0 : (mat == 1) ? w1 : (mat == 2) ? w2
            : (mat == 3) ? w3 : (mat == 4) ? w4 : w5;
        dst = wbf + (size_t)mat * DIM * DIM;
        off = (size_t)k * 8;
    }
    f32x4 av4 = *(const f32x4*)(src + off);
    f32x4 bv4 = *(const f32x4*)(src + off + 4);
    short8 o;
#pragma unroll
    for (int e = 0; e < 4; ++e) { o[e] = fbits(av4[e]); o[e + 4] = fbits(bv4[e]); }
    *(short8*)(dst + off) = o;
}

// ---------------------------------------------------------------------------
// phrase[(p*BSZ+b)*DIM+d] = max_{w<8} query[(8p+w)][b][d]   (fp32 in, bf16 out)
// ---------------------------------------------------------------------------
__global__ void phrase_max_kernel(const float* __restrict__ q, bf16* __restrict__ phrase) {
    int idx = blockIdx.x * 256 + threadIdx.x;
    int d  = idx % DIM;
    int pb = idx / DIM;
    int b  = pb % BSZ;
    int p  = pb / BSZ;
    float m = -1e30f;
#pragma unroll
    for (int w = 0; w < WIN; ++w)
        m = fmaxf(m, q[((size_t)(p * WIN + w) * BSZ + b) * DIM + d]);
    phrase[idx] = f2b(m);
}

// ---------------------------------------------------------------------------
// gvT[bh*HD+hd][p] = sum_j gauss(p,j) * vT[bh*HD+hd][j], banded |j-mu|<=15.5
// ---------------------------------------------------------------------------
__global__ void gauss_v_kernel(const bf16* __restrict__ vT, bf16* __restrict__ gvT) {
    int row = blockIdx.x;               // bh*HD + hd
    int p   = threadIdx.x;              // 0..255
    float mu = p * (float)WIN + (WIN - 1) * 0.5f;
    float acc = 0.f;
    int j0 = p * WIN - 12;
    const bf16* src = vT + (size_t)row * SEQ;
#pragma unroll
    for (int jj = 0; jj < 32; ++jj) {
        int j = j0 + jj;
        if (j < 0 || j >= SEQ) continue;
        float dd = (float)j - mu;
        acc += __expf(-dd * dd * 0.125f) * 0.199471140200716f * b2f(src[j]);
    }
    gvT[(size_t)row * PN + p] = f2b(acc);
}

// ---------------------------------------------------------------------------
// 128x128 GEMM body (m97 pattern, round-1 proven version): C = (A@W^T+b)*scale
// ---------------------------------------------------------------------------
__device__ __forceinline__ void gemm_body(const bf16* __restrict__ A,
                                          const bf16* __restrict__ W,
                                          const float* __restrict__ bias,
                                          void* __restrict__ Cout,
                                          int m0, int n0, float scale,
                                          int mode, int LEN) {
    __shared__ bf16 As[128 * 32];
    __shared__ bf16 Ws[128 * 32];
    int t = threadIdx.x;
    int wave = t >> 6, lane = t & 63;
    int wm = (wave >> 1) * 64, wn = (wave & 1) * 64;
    int l15 = lane & 15, quad = lane >> 4;

    f32x4 acc[4][4] = {};

    for (int k0 = 0; k0 < DIM; k0 += 32) {
        {
            int c0 = t, c1 = t + 256;
            gl_lds16(A + (size_t)(m0 + (c0 >> 2)) * DIM + k0 + (c0 & 3) * 8, &As[c0 * 8]);
            gl_lds16(A + (size_t)(m0 + (c1 >> 2)) * DIM + k0 + (c1 & 3) * 8, &As[c1 * 8]);
            gl_lds16(W + (size_t)(n0 + (c0 >> 2)) * DIM + k0 + (c0 & 3) * 8, &Ws[c0 * 8]);
            gl_lds16(W + (size_t)(n0 + (c1 >> 2)) * DIM + k0 + (c1 & 3) * 8, &Ws[c1 * 8]);
        }
        __syncthreads();
        short8 af[4], bfr[4];
#pragma unroll
        for (int tm = 0; tm < 4; ++tm)
            af[tm] = *(short8*)&As[(wm + tm * 16 + l15) * 32 + quad * 8];
#pragma unroll
        for (int tn = 0; tn < 4; ++tn)
            bfr[tn] = *(short8*)&Ws[(wn + tn * 16 + l15) * 32 + quad * 8];
#pragma unroll
        for (int tm = 0; tm < 4; ++tm)
#pragma unroll
            for (int tn = 0; tn < 4; ++tn)
                acc[tm][tn] = __builtin_amdgcn_mfma_f32_16x16x32_bf16(af[tm], bfr[tn], acc[tm][tn], 0, 0, 0);
        __syncthreads();
    }

#pragma unroll
    for (int tm = 0; tm < 4; ++tm) {
        int mrow = m0 + wm + tm * 16 + quad * 4;
#pragma unroll
        for (int tn = 0; tn < 4; ++tn) {
            int n = n0 + wn + tn * 16 + l15;
            float bsv = bias[n];
#pragma unroll
            for (int r = 0; r < 4; ++r) {
                int m = mrow + r;
                float val = (acc[tm][tn][r] + bsv) * scale;
                int s = m / BSZ, b = m % BSZ;
                int h = n >> 6, hd = n & 63;
                if (mode == 0)
                    ((bf16*)Cout)[((size_t)(b * NH + h) * LEN + s) * HD + hd] = f2b(val);
                else
                    ((bf16*)Cout)[((size_t)(b * NH + h) * HD + hd) * LEN + s] = f2b(val);
            }
        }
    }
}

#define QSCALE (0.125f * 1.44269504088896f)   // fold log2(e) for exp2

// batched projections: z = 0:q_b 1:k_b 2:vT 3:q_g 4:k_g(phrase)
__global__ __launch_bounds__(256) void gemm_proj(const bf16* __restrict__ qbf,
                                                 const bf16* __restrict__ phrasebf,
                                                 const bf16* __restrict__ wbf,
                                                 const float* __restrict__ bias_pack,
                                                 bf16* __restrict__ q_b, bf16* __restrict__ k_b,
                                                 bf16* __restrict__ vT, bf16* __restrict__ q_g,
                                                 bf16* __restrict__ k_g) {
    int z = blockIdx.z;
    const bf16* A = qbf;
    bf16* C;
    int mode = 0, LEN = SEQ;
    float scale = 1.0f;
    switch (z) {
        case 0: C = q_b; scale = QSCALE; break;
        case 1: C = k_b; break;
        case 2: C = vT; mode = 2; break;
        case 3: C = q_g; scale = QSCALE; break;
        default:
            if (blockIdx.x >= 4) return;          // M = 512 for phrase GEMM
            A = phrasebf; C = k_g; LEN = PN; break;
    }
    gemm_body(A, wbf + (size_t)z * DIM * DIM, bias_pack + z * DIM, C,
              blockIdx.x * 128, blockIdx.y * 128, scale, mode, LEN);
}

// ---------------------------------------------------------------------------
// final GEMM: out = attn_bf @ Wo^T + bo (fp32), 64x128 tile (round-1 version)
// ---------------------------------------------------------------------------
__global__ __launch_bounds__(256) void gemm_final(const bf16* __restrict__ A,
                                                  const bf16* __restrict__ wbf,
                                                  const float* __restrict__ bias_pack,
                                                  float* __restrict__ out) {
    __shared__ bf16 As[64 * 32];
    __shared__ bf16 Ws[128 * 32];
    const bf16* W = wbf + (size_t)5 * DIM * DIM;
    const float* bias = bias_pack + 5 * DIM;
    int t = threadIdx.x;
    int m0 = blockIdx.x * 64, n0 = blockIdx.y * 128;
    int wave = t >> 6, lane = t & 63;
    int wm = (wave >> 1) * 32, wn = (wave & 1) * 64;
    int l15 = lane & 15, quad = lane >> 4;

    f32x4 acc[2][4] = {};

    for (int k0 = 0; k0 < DIM; k0 += 32) {
        {
            int c0 = t, c1 = t + 256;
            gl_lds16(A + (size_t)(m0 + (c0 >> 2)) * DIM + k0 + (c0 & 3) * 8, &As[c0 * 8]);
            gl_lds16(W + (size_t)(n0 + (c0 >> 2)) * DIM + k0 + (c0 & 3) * 8, &Ws[c0 * 8]);
            gl_lds16(W + (size_t)(n0 + (c1 >> 2)) * DIM + k0 + (c1 & 3) * 8, &Ws[c1 * 8]);
        }
        __syncthreads();
        short8 af[2], bfr[4];
#pragma unroll
        for (int tm = 0; tm < 2; ++tm)
            af[tm] = *(short8*)&As[(wm + tm * 16 + l15) * 32 + quad * 8];
#pragma unroll
        for (int tn = 0; tn < 4; ++tn)
            bfr[tn] = *(short8*)&Ws[(wn + tn * 16 + l15) * 32 + quad * 8];
#pragma unroll
        for (int tm = 0; tm < 2; ++tm)
#pragma unroll
            for (int tn = 0; tn < 4; ++tn)
                acc[tm][tn] = __builtin_amdgcn_mfma_f32_16x16x32_bf16(af[tm], bfr[tn], acc[tm][tn], 0, 0, 0);
        __syncthreads();
    }

#pragma unroll
    for (int tm = 0; tm < 2; ++tm) {
        int mrow = m0 + wm + tm * 16 + quad * 4;
#pragma unroll
        for (int tn = 0; tn < 4; ++tn) {
            int n = n0 + wn + tn * 16 + l15;
            float bsv = bias[n];
#pragma unroll
            for (int r = 0; r < 4; ++r)
                out[(size_t)(mrow + r) * DIM + n] = acc[tm][tn][r] + bsv;
        }
    }
}

// ---------------------------------------------------------------------------
// MFMA attention v10: ZERO-STAGING / ZERO-BARRIER.  All MFMA operand
// fragments (Q, K, V) load directly from global as 16B/lane reads; K/V are
// XCD-L2-resident (XCD-chunked swizzle).  LDS holds only the P round-trip
// (8 KB, wave-private rows -> no barriers anywhere).  Waves fully
// independent -> VMEM/VALU/LDS/MFMA overlap across the CU's 8 waves instead
// of serializing in barrier-locked chunks (R5 lesson: pipes were summing).
// V-frag loads issue at chunk start so L2 latency hides under QK^T+softmax.
// (Resubmit of round-6 source: bench failure was a container flake, not a
// kernel fault — no barriers to deadlock, all accesses bounds-checked.)
// ---------------------------------------------------------------------------
__global__ __launch_bounds__(128) void attn_kernel(const bf16* __restrict__ qb,
                                                   const bf16* __restrict__ kb,
                                                   const bf16* __restrict__ vT,
                                                   const bf16* __restrict__ qg,
                                                   const bf16* __restrict__ kg,
                                                   const bf16* __restrict__ gvT,
                                                   bf16* __restrict__ out) {
    __shared__ bf16 Ps[64 * 64];   // P only: [qrow][key], swizzled 128B rows

    int t = threadIdx.x;           // 0..127
    int wave = t >> 6, lane = t & 63;
    int l15 = lane & 15, quad = lane >> 4;
    // bijective XCD-chunked swizzle (nwg=1024 = 8*128): same-bh q-blocks share an XCD
    int flat = blockIdx.y * gridDim.x + blockIdx.x;
    int wid = (flat & 7) * 128 + (flat >> 3);
    int q0 = (wid & 31) * 64;
    int bh = wid >> 5;
    int b = bh / NH, h = bh % NH;

    const short8 ones = (short8)0x3F80;   // bf16 1.0 splat

    float result[2][4][4] = {};           // [q-tile][n-tile][row]

    for (int phase = 0; phase < 2; ++phase) {
        const bf16* qptr = phase ? qb : qg;
        const bf16* kptr = phase ? kb : kg;
        const bf16* vtp  = phase ? vT : gvT;
        int kvlen = phase ? SEQ : PN;
        int nchunk = kvlen / 64;

        // Q B-fragments direct from global (chunk-invariant)
        short8 bq[2][2];   // [q-tile][kk]
#pragma unroll
        for (int qt = 0; qt < 2; ++qt) {
            const bf16* qr = qptr + ((size_t)bh * SEQ + q0 + wave * 32 + qt * 16 + l15) * HD + quad * 8;
            bq[qt][0] = *(const short8*)(qr);
            bq[qt][1] = *(const short8*)(qr + 32);
        }

        // per-lane fragment base pointers (advance by pointer increment)
        const bf16* kf = kptr + ((size_t)bh * kvlen + l15) * HD + quad * 8;
        const bf16* vf = vtp + ((size_t)(bh * HD) + l15) * kvlen + quad * 8;

        f32x4 o_acc[2][4] = {};
        f32x4 l_acc[2] = {};
        for (int ch = 0; ch < nchunk; ++ch) {
            // issue all 16 fragment loads up front; V latency hides under QK+softmax
            short8 ak[2][4], vb[2][4];
#pragma unroll
            for (int kk = 0; kk < 2; ++kk)
#pragma unroll
                for (int tn = 0; tn < 4; ++tn) {
                    ak[kk][tn] = *(const short8*)(kf + (size_t)(tn * 16) * HD + kk * 32);
                    vb[kk][tn] = *(const short8*)(vf + (size_t)(tn * 16) * kvlen + kk * 32);
                }
            kf += 64 * HD;
            vf += 64;

            // S^T = K Q^T : D[m=key (4 tiles)][n=qrow (2 tiles of 16)]
            f32x4 s_acc[2][4] = {};
#pragma unroll
            for (int kk = 0; kk < 2; ++kk)
#pragma unroll
                for (int tn = 0; tn < 4; ++tn) {
                    s_acc[0][tn] = __builtin_amdgcn_mfma_f32_16x16x32_bf16(ak[kk][tn], bq[0][kk], s_acc[0][tn], 0, 0, 0);
                    s_acc[1][tn] = __builtin_amdgcn_mfma_f32_16x16x32_bf16(ak[kk][tn], bq[1][kk], s_acc[1][tn], 0, 0, 0);
                }
            // P = exp2(S^T): raw v_exp + perm-pack, 8B store per (qt,tn)
#pragma unroll
            for (int qt = 0; qt < 2; ++qt)
#pragma unroll
                for (int tn = 0; tn < 4; ++tn) {
                    float e0 = __builtin_amdgcn_exp2f(s_acc[qt][tn][0]);
                    float e1 = __builtin_amdgcn_exp2f(s_acc[qt][tn][1]);
                    float e2 = __builtin_amdgcn_exp2f(s_acc[qt][tn][2]);
                    float e3 = __builtin_amdgcn_exp2f(s_acc[qt][tn][3]);
                    uint2v pw;
                    pw[0] = pk2bf(e0, e1);
                    pw[1] = pk2bf(e2, e3);
                    *(uint2v*)swzp(Ps, wave * 32 + qt * 16 + l15, tn * 32 + quad * 8) = pw;
                }
            // PV + rowsum: A = P rows (LDS), B = V frags (regs); no barrier —
            // P rows are wave-private, lgkmcnt orders the within-wave RAW.
#pragma unroll
            for (int kk = 0; kk < 2; ++kk) {
                short8 pa0 = *(short8*)swzp(Ps, wave * 32 + l15,      kk * 64 + quad * 16);
                short8 pa1 = *(short8*)swzp(Ps, wave * 32 + 16 + l15, kk * 64 + quad * 16);
                l_acc[0] = __builtin_amdgcn_mfma_f32_16x16x32_bf16(pa0, ones, l_acc[0], 0, 0, 0);
                l_acc[1] = __builtin_amdgcn_mfma_f32_16x16x32_bf16(pa1, ones, l_acc[1], 0, 0, 0);
#pragma unroll
                for (int tn = 0; tn < 4; ++tn) {
                    o_acc[0][tn] = __builtin_amdgcn_mfma_f32_16x16x32_bf16(pa0, vb[kk][tn], o_acc[0][tn], 0, 0, 0);
                    o_acc[1][tn] = __builtin_amdgcn_mfma_f32_16x16x32_bf16(pa1, vb[kk][tn], o_acc[1][tn], 0, 0, 0);
                }
            }
        }
#pragma unroll
        for (int qt = 0; qt < 2; ++qt)
#pragma unroll
            for (int r = 0; r < 4; ++r) {
                float inv = 0.5f / fmaxf(l_acc[qt][r], 1e-30f);
#pragma unroll
                for (int tn = 0; tn < 4; ++tn)
                    result[qt][tn][r] += o_acc[qt][tn][r] * inv;
            }
    }

    // store attn_bf; O C-layout: col=hd(l15), row=qrow quad*4+r
#pragma unroll
    for (int qt = 0; qt < 2; ++qt)
#pragma unroll
        for (int r = 0; r < 4; ++r) {
            int srow = q0 + wave * 32 + qt * 16 + quad * 4 + r;
            int mm = srow * BSZ + b;
#pragma unroll
            for (int tn = 0; tn < 4; ++tn) {
                int dcol = h * HD + tn * 16 + l15;
                out[(size_t)mm * DIM + dcol] = f2b(result[qt][tn][r]);
            }
        }
}

// ---------------------------------------------------------------------------
extern "C" void kernel_launch(void* const* d_in, const int* in_sizes, int n_in,
                              void* d_out, int out_size, void* d_ws, size_t ws_size,
                              hipStream_t stream) {
    (void)in_sizes; (void)n_in; (void)out_size; (void)ws_size;
    const float* query = (const float*)d_in[0];
    const float* Wq_b  = (const float*)d_in[1];
    const float* bq_b  = (const float*)d_in[2];
    const float* Wk_b  = (const float*)d_in[3];
    const float* bk_b  = (const float*)d_in[4];
    const float* Wq_g  = (const float*)d_in[5];
    const float* bq_g  = (const float*)d_in[6];
    const float* Wk_g  = (const float*)d_in[7];
    const float* bk_g  = (const float*)d_in[8];
    const float* Wv    = (const float*)d_in[9];
    const float* bv    = (const float*)d_in[10];
    const float* Wo    = (const float*)d_in[11];
    const float* bo    = (const float*)d_in[12];
    float* out = (float*)d_out;

    const size_t NQ = (size_t)BSZ * NH * SEQ * HD;   // 4194304
    const size_t NP = (size_t)BSZ * NH * PN * HD;    // 524288
    bf16* qbf      = (bf16*)d_ws;                    // 4M
    bf16* wbf      = qbf + NQ;                       // 6M
    bf16* phrasebf = wbf + (size_t)6 * DIM * DIM;    // 512K
    bf16* q_b      = phrasebf + (size_t)PN * BSZ * DIM;
    bf16* k_b      = q_b + NQ;
    bf16* vT       = k_b + NQ;                       // [bh][hd][s]
    bf16* q_g      = vT + NQ;
    bf16* k_g      = q_g + NQ;                       // [bh][p][hd]
    bf16* gvT      = k_g + NP;                       // [bh][hd][p]
    bf16* attn_bf  = gvT + NP;                       // [m][dcol]
    float* bias_pack = (float*)(attn_bf + NQ);       // 6*1024 fp32

    const int QV = (SEQ * BSZ * DIM) / 8, WV6 = 6 * (DIM * DIM) / 8;
    convert_kernel<<<(QV + WV6) / 256 + 3, 256, 0, stream>>>(
        query, Wq_b, Wk_b, Wv, Wq_g, Wk_g, Wo,
        bq_b, bk_b, bv, bq_g, bk_g, bo, qbf, wbf, bias_pack);
    phrase_max_kernel<<<(PN * BSZ * DIM) / 256, 256, 0, stream>>>(query, phrasebf);

    dim3 gp((SEQ * BSZ) / 128, DIM / 128, 5);
    gemm_proj<<<gp, 256, 0, stream>>>(qbf, phrasebf, wbf, bias_pack,
                                      q_b, k_b, vT, q_g, k_g);

    gauss_v_kernel<<<BSZ * NH * HD, PN, 0, stream>>>(vT, gvT);

    dim3 g3(SEQ / 64, BSZ * NH);
    attn_kernel<<<g3, 128, 0, stream>>>(q_b, k_b, vT, q_g, k_g, gvT, attn_bf);

    dim3 gf((SEQ * BSZ) / 64, DIM / 128);
    gemm_final<<<gf, 256, 0, stream>>>(attn_bf, wbf, bias_pack, out);
}

// Round 8
// 271.306 us; speedup vs baseline: 1.3775x; 1.3775x over previous
//
#include <hip/hip_runtime.h>
#include <hip/hip_bf16.h>

#define SEQ 2048
#define BSZ 2
#define DIM 1024
#define NH 16
#define HD 64
#define WIN 8
#define PN 256

typedef __hip_bfloat16 bf16;
typedef __attribute__((ext_vector_type(8))) short short8;
typedef __attribute__((ext_vector_type(4))) short short4v;
typedef __attribute__((ext_vector_type(2))) unsigned int uint2v;
typedef __attribute__((ext_vector_type(4))) float f32x4;

__device__ __forceinline__ float b2f(bf16 x) { return __bfloat162float(x); }
__device__ __forceinline__ bf16 f2b(float x) { return __float2bfloat16(x); }
__device__ __forceinline__ short fbits(float x) { bf16 h = __float2bfloat16(x); return *(short*)&h; }

// pack two f32 -> two bf16 in one dword: round-half-up (+0x8000) then take the
// high halves via one v_perm_b32.  Differs from RNE only on exact ties.
__device__ __forceinline__ unsigned pk2bf(float lo, float hi) {
    return __builtin_amdgcn_perm(__float_as_uint(hi) + 0x8000u,
                                 __float_as_uint(lo) + 0x8000u, 0x07060302u);
}

// async global->LDS, 16B per lane; LDS dest must be wave-uniform base + lane*16
__device__ __forceinline__ void gl_lds16(const bf16* g, bf16* l) {
    __builtin_amdgcn_global_load_lds((const __attribute__((address_space(1))) void*)g,
                                     (__attribute__((address_space(3))) void*)l, 16, 0, 0);
}

// XOR-swizzled LDS addressing: 128B rows, byte ^= ((row&7)<<4).
__device__ __forceinline__ bf16* swzp(bf16* base, int row, int byteoff) {
    return (bf16*)((char*)base + (row << 7) + (byteoff ^ ((row & 7) << 4)));
}

// ---------------------------------------------------------------------------
// fp32 -> bf16 pre-convert: query (4M) + 6 weights (6M) + bias pack (6K fp32)
// ---------------------------------------------------------------------------
__global__ void convert_kernel(const float* __restrict__ q,
                               const float* __restrict__ w0, const float* __restrict__ w1,
                               const float* __restrict__ w2, const float* __restrict__ w3,
                               const float* __restrict__ w4, const float* __restrict__ w5,
                               const float* __restrict__ b0, const float* __restrict__ b1,
                               const float* __restrict__ b2, const float* __restrict__ b3,
                               const float* __restrict__ b4, const float* __restrict__ b5,
                               bf16* __restrict__ qbf, bf16* __restrict__ wbf,
                               float* __restrict__ bp) {
    int i = blockIdx.x * 256 + threadIdx.x;          // vector idx, 8 floats each
    const int QV = (SEQ * BSZ * DIM) / 8;            // 524288
    const int WV = (DIM * DIM) / 8;                  // 131072
    const int TV = QV + 6 * WV;
    if (i >= TV) {                                   // bias path: 768 chunks
        int j = i - TV;
        if (j >= 768) return;
        int mat = j >> 7, k = (j & 127) * 8;
        const float* s = (mat == 0) ? b0 : (mat == 1) ? b1 : (mat == 2) ? b2
                       : (mat == 3) ? b3 : (mat == 4) ? b4 : b5;
        *(f32x4*)(bp + mat * DIM + k)     = *(const f32x4*)(s + k);
        *(f32x4*)(bp + mat * DIM + k + 4) = *(const f32x4*)(s + k + 4);
        return;
    }
    const float* src;
    bf16* dst;
    size_t off;
    if (i < QV) { src = q; dst = qbf; off = (size_t)i * 8; }
    else {
        int j = i - QV;
        int mat = j / WV, k = j - mat * WV;
        src = (mat == 0) ? w0 : (mat == 1) ? w1 : (mat == 2) ? w2
            : (mat == 3) ? w3 : (mat == 4) ? w4 : w5;
        dst = wbf + (size_t)mat * DIM * DIM;
        off = (size_t)k * 8;
    }
    f32x4 av4 = *(const f32x4*)(src + off);
    f32x4 bv4 = *(const f32x4*)(src + off + 4);
    short8 o;
#pragma unroll
    for (int e = 0; e < 4; ++e) { o[e] = fbits(av4[e]); o[e + 4] = fbits(bv4[e]); }
    *(short8*)(dst + off) = o;
}

// ---------------------------------------------------------------------------
// phrase[(p*BSZ+b)*DIM+d] = max_{w<8} query[(8p+w)][b][d]   (fp32 in, bf16 out)
// ---------------------------------------------------------------------------
__global__ void phrase_max_kernel(const float* __restrict__ q, bf16* __restrict__ phrase) {
    int idx = blockIdx.x * 256 + threadIdx.x;
    int d  = idx % DIM;
    int pb = idx / DIM;
    int b  = pb % BSZ;
    int p  = pb / BSZ;
    float m = -1e30f;
#pragma unroll
    for (int w = 0; w < WIN; ++w)
        m = fmaxf(m, q[((size_t)(p * WIN + w) * BSZ + b) * DIM + d]);
    phrase[idx] = f2b(m);
}

// ---------------------------------------------------------------------------
// gvT[bh*HD+hd][p] = sum_j gauss(p,j) * vT[bh*HD+hd][j], banded |j-mu|<=15.5
// ---------------------------------------------------------------------------
__global__ void gauss_v_kernel(const bf16* __restrict__ vT, bf16* __restrict__ gvT) {
    int row = blockIdx.x;               // bh*HD + hd
    int p   = threadIdx.x;              // 0..255
    float mu = p * (float)WIN + (WIN - 1) * 0.5f;
    float acc = 0.f;
    int j0 = p * WIN - 12;
    const bf16* src = vT + (size_t)row * SEQ;
#pragma unroll
    for (int jj = 0; jj < 32; ++jj) {
        int j = j0 + jj;
        if (j < 0 || j >= SEQ) continue;
        float dd = (float)j - mu;
        acc += __expf(-dd * dd * 0.125f) * 0.199471140200716f * b2f(src[j]);
    }
    gvT[(size_t)row * PN + p] = f2b(acc);
}

// ---------------------------------------------------------------------------
// 128x128 GEMM body, BK=64 + T2 XOR-swizzled LDS (128B rows):
// halves barrier-drain count vs BK=32 (16 K-steps, 32 MFMA per drain).
// Staging writes the swizzled image via pre-swizzled GLOBAL source (rule 21);
// reads apply the same XOR -> conflict-free despite 128B pitch.
// ---------------------------------------------------------------------------
__device__ __forceinline__ void gemm_body(const bf16* __restrict__ A,
                                          const bf16* __restrict__ W,
                                          const float* __restrict__ bias,
                                          void* __restrict__ Cout,
                                          int m0, int n0, float scale,
                                          int mode, int LEN) {
    __shared__ bf16 As[128 * 64];
    __shared__ bf16 Ws[128 * 64];
    int t = threadIdx.x;
    int wave = t >> 6, lane = t & 63;
    int wm = (wave >> 1) * 64, wn = (wave & 1) * 64;
    int l15 = lane & 15, quad = lane >> 4;

    f32x4 acc[4][4] = {};

    for (int k0 = 0; k0 < DIM; k0 += 64) {
#pragma unroll
        for (int u = 0; u < 4; ++u) {           // 1024 slots each, 4/thread
            int i = t + u * 256;
            int row = i >> 3;                   // 8 x 16B slots per 128B row
            int cb = ((i & 7) * 16) ^ ((row & 7) << 4);
            gl_lds16(A + (size_t)(m0 + row) * DIM + k0 + (cb >> 1), &As[i * 8]);
            gl_lds16(W + (size_t)(n0 + row) * DIM + k0 + (cb >> 1), &Ws[i * 8]);
        }
        __syncthreads();
#pragma unroll
        for (int kk = 0; kk < 2; ++kk) {
            short8 af[4], bfr[4];
#pragma unroll
            for (int tm = 0; tm < 4; ++tm) {
                int r = wm + tm * 16 + l15;
                af[tm] = *(short8*)((char*)As + r * 128 + ((kk * 64 + quad * 16) ^ ((r & 7) << 4)));
            }
#pragma unroll
            for (int tn = 0; tn < 4; ++tn) {
                int r = wn + tn * 16 + l15;
                bfr[tn] = *(short8*)((char*)Ws + r * 128 + ((kk * 64 + quad * 16) ^ ((r & 7) << 4)));
            }
#pragma unroll
            for (int tm = 0; tm < 4; ++tm)
#pragma unroll
                for (int tn = 0; tn < 4; ++tn)
                    acc[tm][tn] = __builtin_amdgcn_mfma_f32_16x16x32_bf16(af[tm], bfr[tn], acc[tm][tn], 0, 0, 0);
        }
        __syncthreads();
    }

#pragma unroll
    for (int tm = 0; tm < 4; ++tm) {
        int mrow = m0 + wm + tm * 16 + quad * 4;
#pragma unroll
        for (int tn = 0; tn < 4; ++tn) {
            int n = n0 + wn + tn * 16 + l15;
            float bsv = bias[n];
#pragma unroll
            for (int r = 0; r < 4; ++r) {
                int m = mrow + r;
                float val = (acc[tm][tn][r] + bsv) * scale;
                int s = m / BSZ, b = m % BSZ;
                int h = n >> 6, hd = n & 63;
                if (mode == 0)
                    ((bf16*)Cout)[((size_t)(b * NH + h) * LEN + s) * HD + hd] = f2b(val);
                else
                    ((bf16*)Cout)[((size_t)(b * NH + h) * HD + hd) * LEN + s] = f2b(val);
            }
        }
    }
}

#define QSCALE (0.125f * 1.44269504088896f)   // fold log2(e) for exp2

// batched projections: z = 0:q_b 1:k_b 2:vT 3:q_g 4:k_g(phrase)
__global__ __launch_bounds__(256) void gemm_proj(const bf16* __restrict__ qbf,
                                                 const bf16* __restrict__ phrasebf,
                                                 const bf16* __restrict__ wbf,
                                                 const float* __restrict__ bias_pack,
                                                 bf16* __restrict__ q_b, bf16* __restrict__ k_b,
                                                 bf16* __restrict__ vT, bf16* __restrict__ q_g,
                                                 bf16* __restrict__ k_g) {
    int z = blockIdx.z;
    const bf16* A = qbf;
    bf16* C;
    int mode = 0, LEN = SEQ;
    float scale = 1.0f;
    switch (z) {
        case 0: C = q_b; scale = QSCALE; break;
        case 1: C = k_b; break;
        case 2: C = vT; mode = 2; break;
        case 3: C = q_g; scale = QSCALE; break;
        default:
            if (blockIdx.x >= 4) return;          // M = 512 for phrase GEMM
            A = phrasebf; C = k_g; LEN = PN; break;
    }
    gemm_body(A, wbf + (size_t)z * DIM * DIM, bias_pack + z * DIM, C,
              blockIdx.x * 128, blockIdx.y * 128, scale, mode, LEN);
}

// ---------------------------------------------------------------------------
// final GEMM: out = attn_bf @ Wo^T + bo (fp32), 64x128 tile, BK=64 swizzled.
// ---------------------------------------------------------------------------
__global__ __launch_bounds__(256) void gemm_final(const bf16* __restrict__ A,
                                                  const bf16* __restrict__ wbf,
                                                  const float* __restrict__ bias_pack,
                                                  float* __restrict__ out) {
    __shared__ bf16 As[64 * 64];
    __shared__ bf16 Ws[128 * 64];
    const bf16* W = wbf + (size_t)5 * DIM * DIM;
    const float* bias = bias_pack + 5 * DIM;
    int t = threadIdx.x;
    int m0 = blockIdx.x * 64, n0 = blockIdx.y * 128;
    int wave = t >> 6, lane = t & 63;
    int wm = (wave >> 1) * 32, wn = (wave & 1) * 64;
    int l15 = lane & 15, quad = lane >> 4;

    f32x4 acc[2][4] = {};

    for (int k0 = 0; k0 < DIM; k0 += 64) {
        {
            int i = t;                           // A: 512 slots, 2/thread
            int row = i >> 3;
            int cb = ((i & 7) * 16) ^ ((row & 7) << 4);
            gl_lds16(A + (size_t)(m0 + row) * DIM + k0 + (cb >> 1), &As[i * 8]);
            i = t + 256; row = i >> 3;
            cb = ((i & 7) * 16) ^ ((row & 7) << 4);
            gl_lds16(A + (size_t)(m0 + row) * DIM + k0 + (cb >> 1), &As[i * 8]);
        }
#pragma unroll
        for (int u = 0; u < 4; ++u) {            // W: 1024 slots, 4/thread
            int i = t + u * 256;
            int row = i >> 3;
            int cb = ((i & 7) * 16) ^ ((row & 7) << 4);
            gl_lds16(W + (size_t)(n0 + row) * DIM + k0 + (cb >> 1), &Ws[i * 8]);
        }
        __syncthreads();
#pragma unroll
        for (int kk = 0; kk < 2; ++kk) {
            short8 af[2], bfr[4];
#pragma unroll
            for (int tm = 0; tm < 2; ++tm) {
                int r = wm + tm * 16 + l15;
                af[tm] = *(short8*)((char*)As + r * 128 + ((kk * 64 + quad * 16) ^ ((r & 7) << 4)));
            }
#pragma unroll
            for (int tn = 0; tn < 4; ++tn) {
                int r = wn + tn * 16 + l15;
                bfr[tn] = *(short8*)((char*)Ws + r * 128 + ((kk * 64 + quad * 16) ^ ((r & 7) << 4)));
            }
#pragma unroll
            for (int tm = 0; tm < 2; ++tm)
#pragma unroll
                for (int tn = 0; tn < 4; ++tn)
                    acc[tm][tn] = __builtin_amdgcn_mfma_f32_16x16x32_bf16(af[tm], bfr[tn], acc[tm][tn], 0, 0, 0);
        }
        __syncthreads();
    }

#pragma unroll
    for (int tm = 0; tm < 2; ++tm) {
        int mrow = m0 + wm + tm * 16 + quad * 4;
#pragma unroll
        for (int tn = 0; tn < 4; ++tn) {
            int n = n0 + wn + tn * 16 + l15;
            float bsv = bias[n];
#pragma unroll
            for (int r = 0; r < 4; ++r)
                out[(size_t)(mrow + r) * DIM + n] = acc[tm][tn][r] + bsv;
        }
    }
}

// ---------------------------------------------------------------------------
// MFMA attention v9 (exact round-5 best: 74.8us): 64-row q-blocks, TWO waves
// x 32 qrows (128 threads), 2-barrier chunk loop, register-prefetch staging,
// swizzled LDS, XCD-chunked block swizzle, VALU diet (raw v_exp + perm-pack).
// LDS 24 KB.
// ---------------------------------------------------------------------------
__global__ __launch_bounds__(128) void attn_kernel(const bf16* __restrict__ qb,
                                                   const bf16* __restrict__ kb,
                                                   const bf16* __restrict__ vT,
                                                   const bf16* __restrict__ qg,
                                                   const bf16* __restrict__ kg,
                                                   const bf16* __restrict__ gvT,
                                                   bf16* __restrict__ out) {
    __shared__ bf16 QPs[64 * 64];  // Q during hoist, then Ps[qrow][key]; swizzled
    __shared__ bf16 Ks[64 * 64];   // [key][hd]; swizzled
    __shared__ bf16 Vt[64 * 64];   // [hd][key]; swizzled

    int t = threadIdx.x;           // 0..127
    int wave = t >> 6, lane = t & 63;
    int l15 = lane & 15, quad = lane >> 4;
    // bijective XCD-chunked swizzle (nwg=1024 = 8*128): same-bh q-blocks share an XCD
    int flat = blockIdx.y * gridDim.x + blockIdx.x;
    int wid = (flat & 7) * 128 + (flat >> 3);
    int q0 = (wid & 31) * 64;
    int bh = wid >> 5;
    int b = bh / NH, h = bh % NH;

    const short8 ones = (short8)0x3F80;   // bf16 1.0 splat

    float result[2][4][4] = {};           // [q-tile][n-tile][row]

    for (int phase = 0; phase < 2; ++phase) {
        const bf16* qptr = phase ? qb : qg;
        const bf16* kptr = phase ? kb : kg;
        const bf16* vtp  = phase ? vT : gvT;
        int kvlen = phase ? SEQ : PN;
        int nchunk = kvlen / 64;

        __syncthreads();   // prior phase's P reads done before Q restage
        {
            int r = t >> 1, cb = (t & 1) * 64;   // 64 rows x 128B, 64B/thread
            const bf16* qsrc = qptr + ((size_t)bh * SEQ + q0 + r) * HD + (t & 1) * 32;
            *(short8*)swzp(QPs, r, cb)      = *(const short8*)(qsrc);
            *(short8*)swzp(QPs, r, cb + 16) = *(const short8*)(qsrc + 8);
            *(short8*)swzp(QPs, r, cb + 32) = *(const short8*)(qsrc + 16);
            *(short8*)swzp(QPs, r, cb + 48) = *(const short8*)(qsrc + 24);
        }
        __syncthreads();   // Q visible
        // hoist chunk-invariant Q B-fragments (this wave's 32 q-rows)
        short8 bq[2][2];   // [q-tile][kk]
#pragma unroll
        for (int qt = 0; qt < 2; ++qt) {
            int r = wave * 32 + qt * 16 + l15;
            bq[qt][0] = *(short8*)swzp(QPs, r, quad * 16);
            bq[qt][1] = *(short8*)swzp(QPs, r, 64 + quad * 16);
        }
        // (each wave's P region == its own Q rows; no cross-wave QPs hazard)

        int sr = t >> 1, sb = (t & 1) * 64;      // staging row / byte-col (64B/thread)
        const bf16* kbase = kptr + ((size_t)bh * kvlen + sr) * HD + (t & 1) * 32;
        const bf16* vbase = vtp + (size_t)(bh * HD + sr) * kvlen + (t & 1) * 32;

        // prefetch chunk 0; advance by pointer increment
        const bf16* kn = kbase;
        const bf16* vn = vbase;
        short8 kr[4], vr[4];
#pragma unroll
        for (int j = 0; j < 4; ++j) {
            kr[j] = *(const short8*)(kn + j * 8);
            vr[j] = *(const short8*)(vn + j * 8);
        }

        f32x4 o_acc[2][4] = {};
        f32x4 l_acc[2] = {};
        for (int ch = 0; ch < nchunk; ++ch) {
            __syncthreads();   // prev chunk's Ks/Vt reads done
#pragma unroll
            for (int j = 0; j < 4; ++j) {
                *(short8*)swzp(Ks, sr, sb + j * 16) = kr[j];
                *(short8*)swzp(Vt, sr, sb + j * 16) = vr[j];
            }
            if (ch + 1 < nchunk) {     // prefetch next chunk over compute
                kn += 64 * HD;
                vn += 64;
#pragma unroll
                for (int j = 0; j < 4; ++j) {
                    kr[j] = *(const short8*)(kn + j * 8);
                    vr[j] = *(const short8*)(vn + j * 8);
                }
            }
            __syncthreads();

            // S^T = K Q^T : D[m=key (4 tiles)][n=qrow (2 tiles of 16)]
            f32x4 s_acc[2][4] = {};
#pragma unroll
            for (int kk = 0; kk < 2; ++kk) {
#pragma unroll
                for (int tn = 0; tn < 4; ++tn) {
                    short8 ak = *(short8*)swzp(Ks, tn * 16 + l15, kk * 64 + quad * 16);
                    s_acc[0][tn] = __builtin_amdgcn_mfma_f32_16x16x32_bf16(ak, bq[0][kk], s_acc[0][tn], 0, 0, 0);
                    s_acc[1][tn] = __builtin_amdgcn_mfma_f32_16x16x32_bf16(ak, bq[1][kk], s_acc[1][tn], 0, 0, 0);
                }
            }
            // P = exp2(S^T): raw v_exp + perm-pack, 8B store per (qt,tn)
#pragma unroll
            for (int qt = 0; qt < 2; ++qt)
#pragma unroll
                for (int tn = 0; tn < 4; ++tn) {
                    float e0 = __builtin_amdgcn_exp2f(s_acc[qt][tn][0]);
                    float e1 = __builtin_amdgcn_exp2f(s_acc[qt][tn][1]);
                    float e2 = __builtin_amdgcn_exp2f(s_acc[qt][tn][2]);
                    float e3 = __builtin_amdgcn_exp2f(s_acc[qt][tn][3]);
                    uint2v pw;
                    pw[0] = pk2bf(e0, e1);
                    pw[1] = pk2bf(e2, e3);
                    *(uint2v*)swzp(QPs, wave * 32 + qt * 16 + l15, tn * 32 + quad * 8) = pw;
                }
            // PV + rowsum: A = P rows, B = Vt rows (V-frags serve both q-tiles)
#pragma unroll
            for (int kk = 0; kk < 2; ++kk) {
                short8 pa0 = *(short8*)swzp(QPs, wave * 32 + l15,      kk * 64 + quad * 16);
                short8 pa1 = *(short8*)swzp(QPs, wave * 32 + 16 + l15, kk * 64 + quad * 16);
                l_acc[0] = __builtin_amdgcn_mfma_f32_16x16x32_bf16(pa0, ones, l_acc[0], 0, 0, 0);
                l_acc[1] = __builtin_amdgcn_mfma_f32_16x16x32_bf16(pa1, ones, l_acc[1], 0, 0, 0);
#pragma unroll
                for (int tn = 0; tn < 4; ++tn) {
                    short8 vb = *(short8*)swzp(Vt, tn * 16 + l15, kk * 64 + quad * 16);
                    o_acc[0][tn] = __builtin_amdgcn_mfma_f32_16x16x32_bf16(pa0, vb, o_acc[0][tn], 0, 0, 0);
                    o_acc[1][tn] = __builtin_amdgcn_mfma_f32_16x16x32_bf16(pa1, vb, o_acc[1][tn], 0, 0, 0);
                }
            }
        }
#pragma unroll
        for (int qt = 0; qt < 2; ++qt)
#pragma unroll
            for (int r = 0; r < 4; ++r) {
                float inv = 0.5f / fmaxf(l_acc[qt][r], 1e-30f);
#pragma unroll
                for (int tn = 0; tn < 4; ++tn)
                    result[qt][tn][r] += o_acc[qt][tn][r] * inv;
            }
    }

    // store attn_bf; O C-layout: col=hd(l15), row=qrow quad*4+r
#pragma unroll
    for (int qt = 0; qt < 2; ++qt)
#pragma unroll
        for (int r = 0; r < 4; ++r) {
            int srow = q0 + wave * 32 + qt * 16 + quad * 4 + r;
            int mm = srow * BSZ + b;
#pragma unroll
            for (int tn = 0; tn < 4; ++tn) {
                int dcol = h * HD + tn * 16 + l15;
                out[(size_t)mm * DIM + dcol] = f2b(result[qt][tn][r]);
            }
        }
}

// ---------------------------------------------------------------------------
extern "C" void kernel_launch(void* const* d_in, const int* in_sizes, int n_in,
                              void* d_out, int out_size, void* d_ws, size_t ws_size,
                              hipStream_t stream) {
    (void)in_sizes; (void)n_in; (void)out_size; (void)ws_size;
    const float* query = (const float*)d_in[0];
    const float* Wq_b  = (const float*)d_in[1];
    const float* bq_b  = (const float*)d_in[2];
    const float* Wk_b  = (const float*)d_in[3];
    const float* bk_b  = (const float*)d_in[4];
    const float* Wq_g  = (const float*)d_in[5];
    const float* bq_g  = (const float*)d_in[6];
    const float* Wk_g  = (const float*)d_in[7];
    const float* bk_g  = (const float*)d_in[8];
    const float* Wv    = (const float*)d_in[9];
    const float* bv    = (const float*)d_in[10];
    const float* Wo    = (const float*)d_in[11];
    const float* bo    = (const float*)d_in[12];
    float* out = (float*)d_out;

    const size_t NQ = (size_t)BSZ * NH * SEQ * HD;   // 4194304
    const size_t NP = (size_t)BSZ * NH * PN * HD;    // 524288
    bf16* qbf      = (bf16*)d_ws;                    // 4M
    bf16* wbf      = qbf + NQ;                       // 6M
    bf16* phrasebf = wbf + (size_t)6 * DIM * DIM;    // 512K
    bf16* q_b      = phrasebf + (size_t)PN * BSZ * DIM;
    bf16* k_b      = q_b + NQ;
    bf16* vT       = k_b + NQ;                       // [bh][hd][s]
    bf16* q_g      = vT + NQ;
    bf16* k_g      = q_g + NQ;                       // [bh][p][hd]
    bf16* gvT      = k_g + NP;                       // [bh][hd][p]
    bf16* attn_bf  = gvT + NP;                       // [m][dcol]
    float* bias_pack = (float*)(attn_bf + NQ);       // 6*1024 fp32

    const int QV = (SEQ * BSZ * DIM) / 8, WV6 = 6 * (DIM * DIM) / 8;
    convert_kernel<<<(QV + WV6) / 256 + 3, 256, 0, stream>>>(
        query, Wq_b, Wk_b, Wv, Wq_g, Wk_g, Wo,
        bq_b, bk_b, bv, bq_g, bk_g, bo, qbf, wbf, bias_pack);
    phrase_max_kernel<<<(PN * BSZ * DIM) / 256, 256, 0, stream>>>(query, phrasebf);

    dim3 gp((SEQ * BSZ) / 128, DIM / 128, 5);
    gemm_proj<<<gp, 256, 0, stream>>>(qbf, phrasebf, wbf, bias_pack,
                                      q_b, k_b, vT, q_g, k_g);

    gauss_v_kernel<<<BSZ * NH * HD, PN, 0, stream>>>(vT, gvT);

    dim3 g3(SEQ / 64, BSZ * NH);
    attn_kernel<<<g3, 128, 0, stream>>>(q_b, k_b, vT, q_g, k_g, gvT, attn_bf);

    dim3 gf((SEQ * BSZ) / 64, DIM / 128);
    gemm_final<<<gf, 256, 0, stream>>>(attn_bf, wbf, bias_pack, out);
}

// Round 9
// 265.958 us; speedup vs baseline: 1.4052x; 1.0201x over previous
//
#include <hip/hip_runtime.h>
#include <hip/hip_bf16.h>

#define SEQ 2048
#define BSZ 2
#define DIM 1024
#define NH 16
#define HD 64
#define WIN 8
#define PN 256

typedef __hip_bfloat16 bf16;
typedef __attribute__((ext_vector_type(8))) short short8;
typedef __attribute__((ext_vector_type(4))) short short4v;
typedef __attribute__((ext_vector_type(2))) unsigned int uint2v;
typedef __attribute__((ext_vector_type(4))) float f32x4;

__device__ __forceinline__ float b2f(bf16 x) { return __bfloat162float(x); }
__device__ __forceinline__ bf16 f2b(float x) { return __float2bfloat16(x); }
__device__ __forceinline__ short fbits(float x) { bf16 h = __float2bfloat16(x); return *(short*)&h; }

// pack two f32 -> two bf16 in one dword: round-half-up (+0x8000) then take the
// high halves via one v_perm_b32.  Differs from RNE only on exact ties.
__device__ __forceinline__ unsigned pk2bf(float lo, float hi) {
    return __builtin_amdgcn_perm(__float_as_uint(hi) + 0x8000u,
                                 __float_as_uint(lo) + 0x8000u, 0x07060302u);
}

// async global->LDS, 16B per lane; LDS dest must be wave-uniform base + lane*16
__device__ __forceinline__ void gl_lds16(const bf16* g, bf16* l) {
    __builtin_amdgcn_global_load_lds((const __attribute__((address_space(1))) void*)g,
                                     (__attribute__((address_space(3))) void*)l, 16, 0, 0);
}

// XOR-swizzled LDS addressing: 128B rows, byte ^= ((row&7)<<4).
__device__ __forceinline__ bf16* swzp(bf16* base, int row, int byteoff) {
    return (bf16*)((char*)base + (row << 7) + (byteoff ^ ((row & 7) << 4)));
}

// ---------------------------------------------------------------------------
// fp32 -> bf16 pre-convert: query (4M) + 6 weights (6M) + bias pack (6K fp32)
// ---------------------------------------------------------------------------
__global__ void convert_kernel(const float* __restrict__ q,
                               const float* __restrict__ w0, const float* __restrict__ w1,
                               const float* __restrict__ w2, const float* __restrict__ w3,
                               const float* __restrict__ w4, const float* __restrict__ w5,
                               const float* __restrict__ b0, const float* __restrict__ b1,
                               const float* __restrict__ b2, const float* __restrict__ b3,
                               const float* __restrict__ b4, const float* __restrict__ b5,
                               bf16* __restrict__ qbf, bf16* __restrict__ wbf,
                               float* __restrict__ bp) {
    int i = blockIdx.x * 256 + threadIdx.x;          // vector idx, 8 floats each
    const int QV = (SEQ * BSZ * DIM) / 8;            // 524288
    const int WV = (DIM * DIM) / 8;                  // 131072
    const int TV = QV + 6 * WV;
    if (i >= TV) {                                   // bias path: 768 chunks
        int j = i - TV;
        if (j >= 768) return;
        int mat = j >> 7, k = (j & 127) * 8;
        const float* s = (mat == 0) ? b0 : (mat == 1) ? b1 : (mat == 2) ? b2
                       : (mat == 3) ? b3 : (mat == 4) ? b4 : b5;
        *(f32x4*)(bp + mat * DIM + k)     = *(const f32x4*)(s + k);
        *(f32x4*)(bp + mat * DIM + k + 4) = *(const f32x4*)(s + k + 4);
        return;
    }
    const float* src;
    bf16* dst;
    size_t off;
    if (i < QV) { src = q; dst = qbf; off = (size_t)i * 8; }
    else {
        int j = i - QV;
        int mat = j / WV, k = j - mat * WV;
        src = (mat == 0) ? w0 : (mat == 1) ? w1 : (mat == 2) ? w2
            : (mat == 3) ? w3 : (mat == 4) ? w4 : w5;
        dst = wbf + (size_t)mat * DIM * DIM;
        off = (size_t)k * 8;
    }
    f32x4 av4 = *(const f32x4*)(src + off);
    f32x4 bv4 = *(const f32x4*)(src + off + 4);
    short8 o;
#pragma unroll
    for (int e = 0; e < 4; ++e) { o[e] = fbits(av4[e]); o[e + 4] = fbits(bv4[e]); }
    *(short8*)(dst + off) = o;
}

// ---------------------------------------------------------------------------
// phrase[(p*BSZ+b)*DIM+d] = max_{w<8} query[(8p+w)][b][d]   (fp32 in, bf16 out)
// ---------------------------------------------------------------------------
__global__ void phrase_max_kernel(const float* __restrict__ q, bf16* __restrict__ phrase) {
    int idx = blockIdx.x * 256 + threadIdx.x;
    int d  = idx % DIM;
    int pb = idx / DIM;
    int b  = pb % BSZ;
    int p  = pb / BSZ;
    float m = -1e30f;
#pragma unroll
    for (int w = 0; w < WIN; ++w)
        m = fmaxf(m, q[((size_t)(p * WIN + w) * BSZ + b) * DIM + d]);
    phrase[idx] = f2b(m);
}

// ---------------------------------------------------------------------------
// gvT[bh*HD+hd][p] = sum_j gauss(p,j) * vT[bh*HD+hd][j], banded |j-mu|<=15.5
// ---------------------------------------------------------------------------
__global__ void gauss_v_kernel(const bf16* __restrict__ vT, bf16* __restrict__ gvT) {
    int row = blockIdx.x;               // bh*HD + hd
    int p   = threadIdx.x;              // 0..255
    float mu = p * (float)WIN + (WIN - 1) * 0.5f;
    float acc = 0.f;
    int j0 = p * WIN - 12;
    const bf16* src = vT + (size_t)row * SEQ;
#pragma unroll
    for (int jj = 0; jj < 32; ++jj) {
        int j = j0 + jj;
        if (j < 0 || j >= SEQ) continue;
        float dd = (float)j - mu;
        acc += __expf(-dd * dd * 0.125f) * 0.199471140200716f * b2f(src[j]);
    }
    gvT[(size_t)row * PN + p] = f2b(acc);
}

// ---------------------------------------------------------------------------
// 128x128 GEMM body, 2-PHASE double-buffered (T3-minimum recipe):
//   STAGE(0); vmcnt0+barrier;
//   loop { STAGE(next->buf^1); ds_read+MFMA(buf); ONE barrier; }
// The barrier that drains a tile's loads is a full ds_read+MFMA phase after
// issue -> L2 latency hidden.  BK=64, XOR-swizzled LDS (0 conflicts, R8-
// verified).  T5 setprio around the MFMA cluster.  LDS 64 KB -> 2 blocks/CU.
// ---------------------------------------------------------------------------
__device__ __forceinline__ void gemm_body(const bf16* __restrict__ A,
                                          const bf16* __restrict__ W,
                                          const float* __restrict__ bias,
                                          void* __restrict__ Cout,
                                          int m0, int n0, float scale,
                                          int mode, int LEN) {
    __shared__ bf16 As[2][128 * 64];
    __shared__ bf16 Ws[2][128 * 64];
    int t = threadIdx.x;
    int wave = t >> 6, lane = t & 63;
    int wm = (wave >> 1) * 64, wn = (wave & 1) * 64;
    int l15 = lane & 15, quad = lane >> 4;

    f32x4 acc[4][4] = {};

    // prologue: stage K-tile 0 into buf 0, drain, barrier
#pragma unroll
    for (int u = 0; u < 4; ++u) {
        int i = t + u * 256;
        int row = i >> 3;
        int cb = ((i & 7) * 16) ^ ((row & 7) << 4);
        gl_lds16(A + (size_t)(m0 + row) * DIM + (cb >> 1), &As[0][i * 8]);
        gl_lds16(W + (size_t)(n0 + row) * DIM + (cb >> 1), &Ws[0][i * 8]);
    }
    __syncthreads();

    const int NT = DIM / 64;   // 16 K-tiles
    for (int kt = 0; kt < NT; ++kt) {
        int cur = kt & 1;
        if (kt + 1 < NT) {     // stage next tile; drained by END-of-iter barrier
            int k0 = (kt + 1) * 64, nb = cur ^ 1;
#pragma unroll
            for (int u = 0; u < 4; ++u) {
                int i = t + u * 256;
                int row = i >> 3;
                int cb = ((i & 7) * 16) ^ ((row & 7) << 4);
                gl_lds16(A + (size_t)(m0 + row) * DIM + k0 + (cb >> 1), &As[nb][i * 8]);
                gl_lds16(W + (size_t)(n0 + row) * DIM + k0 + (cb >> 1), &Ws[nb][i * 8]);
            }
        }
#pragma unroll
        for (int kk = 0; kk < 2; ++kk) {
            short8 af[4], bfr[4];
#pragma unroll
            for (int tm = 0; tm < 4; ++tm) {
                int r = wm + tm * 16 + l15;
                af[tm] = *(short8*)((char*)As[cur] + r * 128 + ((kk * 64 + quad * 16) ^ ((r & 7) << 4)));
            }
#pragma unroll
            for (int tn = 0; tn < 4; ++tn) {
                int r = wn + tn * 16 + l15;
                bfr[tn] = *(short8*)((char*)Ws[cur] + r * 128 + ((kk * 64 + quad * 16) ^ ((r & 7) << 4)));
            }
            __builtin_amdgcn_s_setprio(1);
#pragma unroll
            for (int tm = 0; tm < 4; ++tm)
#pragma unroll
                for (int tn = 0; tn < 4; ++tn)
                    acc[tm][tn] = __builtin_amdgcn_mfma_f32_16x16x32_bf16(af[tm], bfr[tn], acc[tm][tn], 0, 0, 0);
            __builtin_amdgcn_s_setprio(0);
        }
        __syncthreads();   // one barrier/K-tile: drains next-tile vmcnt + all lgkm
    }

#pragma unroll
    for (int tm = 0; tm < 4; ++tm) {
        int mrow = m0 + wm + tm * 16 + quad * 4;
#pragma unroll
        for (int tn = 0; tn < 4; ++tn) {
            int n = n0 + wn + tn * 16 + l15;
            float bsv = bias[n];
#pragma unroll
            for (int r = 0; r < 4; ++r) {
                int m = mrow + r;
                float val = (acc[tm][tn][r] + bsv) * scale;
                int s = m / BSZ, b = m % BSZ;
                int h = n >> 6, hd = n & 63;
                if (mode == 0)
                    ((bf16*)Cout)[((size_t)(b * NH + h) * LEN + s) * HD + hd] = f2b(val);
                else
                    ((bf16*)Cout)[((size_t)(b * NH + h) * HD + hd) * LEN + s] = f2b(val);
            }
        }
    }
}

#define QSCALE (0.125f * 1.44269504088896f)   // fold log2(e) for exp2

// batched projections: z = 0:q_b 1:k_b 2:vT 3:q_g 4:k_g(phrase)
__global__ __launch_bounds__(256) void gemm_proj(const bf16* __restrict__ qbf,
                                                 const bf16* __restrict__ phrasebf,
                                                 const bf16* __restrict__ wbf,
                                                 const float* __restrict__ bias_pack,
                                                 bf16* __restrict__ q_b, bf16* __restrict__ k_b,
                                                 bf16* __restrict__ vT, bf16* __restrict__ q_g,
                                                 bf16* __restrict__ k_g) {
    int z = blockIdx.z;
    const bf16* A = qbf;
    bf16* C;
    int mode = 0, LEN = SEQ;
    float scale = 1.0f;
    switch (z) {
        case 0: C = q_b; scale = QSCALE; break;
        case 1: C = k_b; break;
        case 2: C = vT; mode = 2; break;
        case 3: C = q_g; scale = QSCALE; break;
        default:
            if (blockIdx.x >= 4) return;          // M = 512 for phrase GEMM
            A = phrasebf; C = k_g; LEN = PN; break;
    }
    gemm_body(A, wbf + (size_t)z * DIM * DIM, bias_pack + z * DIM, C,
              blockIdx.x * 128, blockIdx.y * 128, scale, mode, LEN);
}

// ---------------------------------------------------------------------------
// final GEMM: out = attn_bf @ Wo^T + bo (fp32), 64x128 tile, BK=64 swizzled
// (R8-verified, untouched this round for clean attribution).
// ---------------------------------------------------------------------------
__global__ __launch_bounds__(256) void gemm_final(const bf16* __restrict__ A,
                                                  const bf16* __restrict__ wbf,
                                                  const float* __restrict__ bias_pack,
                                                  float* __restrict__ out) {
    __shared__ bf16 As[64 * 64];
    __shared__ bf16 Ws[128 * 64];
    const bf16* W = wbf + (size_t)5 * DIM * DIM;
    const float* bias = bias_pack + 5 * DIM;
    int t = threadIdx.x;
    int m0 = blockIdx.x * 64, n0 = blockIdx.y * 128;
    int wave = t >> 6, lane = t & 63;
    int wm = (wave >> 1) * 32, wn = (wave & 1) * 64;
    int l15 = lane & 15, quad = lane >> 4;

    f32x4 acc[2][4] = {};

    for (int k0 = 0; k0 < DIM; k0 += 64) {
        {
            int i = t;                           // A: 512 slots, 2/thread
            int row = i >> 3;
            int cb = ((i & 7) * 16) ^ ((row & 7) << 4);
            gl_lds16(A + (size_t)(m0 + row) * DIM + k0 + (cb >> 1), &As[i * 8]);
            i = t + 256; row = i >> 3;
            cb = ((i & 7) * 16) ^ ((row & 7) << 4);
            gl_lds16(A + (size_t)(m0 + row) * DIM + k0 + (cb >> 1), &As[i * 8]);
        }
#pragma unroll
        for (int u = 0; u < 4; ++u) {            // W: 1024 slots, 4/thread
            int i = t + u * 256;
            int row = i >> 3;
            int cb = ((i & 7) * 16) ^ ((row & 7) << 4);
            gl_lds16(W + (size_t)(n0 + row) * DIM + k0 + (cb >> 1), &Ws[i * 8]);
        }
        __syncthreads();
#pragma unroll
        for (int kk = 0; kk < 2; ++kk) {
            short8 af[2], bfr[4];
#pragma unroll
            for (int tm = 0; tm < 2; ++tm) {
                int r = wm + tm * 16 + l15;
                af[tm] = *(short8*)((char*)As + r * 128 + ((kk * 64 + quad * 16) ^ ((r & 7) << 4)));
            }
#pragma unroll
            for (int tn = 0; tn < 4; ++tn) {
                int r = wn + tn * 16 + l15;
                bfr[tn] = *(short8*)((char*)Ws + r * 128 + ((kk * 64 + quad * 16) ^ ((r & 7) << 4)));
            }
#pragma unroll
            for (int tm = 0; tm < 2; ++tm)
#pragma unroll
                for (int tn = 0; tn < 4; ++tn)
                    acc[tm][tn] = __builtin_amdgcn_mfma_f32_16x16x32_bf16(af[tm], bfr[tn], acc[tm][tn], 0, 0, 0);
        }
        __syncthreads();
    }

#pragma unroll
    for (int tm = 0; tm < 2; ++tm) {
        int mrow = m0 + wm + tm * 16 + quad * 4;
#pragma unroll
        for (int tn = 0; tn < 4; ++tn) {
            int n = n0 + wn + tn * 16 + l15;
            float bsv = bias[n];
#pragma unroll
            for (int r = 0; r < 4; ++r)
                out[(size_t)(mrow + r) * DIM + n] = acc[tm][tn][r] + bsv;
        }
    }
}

// ---------------------------------------------------------------------------
// MFMA attention v9 (round-5 best, untouched): 64-row q-blocks, TWO waves
// x 32 qrows (128 threads), 2-barrier chunk loop, register-prefetch staging,
// swizzled LDS, XCD-chunked block swizzle, VALU diet.  LDS 24 KB.
// ---------------------------------------------------------------------------
__global__ __launch_bounds__(128) void attn_kernel(const bf16* __restrict__ qb,
                                                   const bf16* __restrict__ kb,
                                                   const bf16* __restrict__ vT,
                                                   const bf16* __restrict__ qg,
                                                   const bf16* __restrict__ kg,
                                                   const bf16* __restrict__ gvT,
                                                   bf16* __restrict__ out) {
    __shared__ bf16 QPs[64 * 64];  // Q during hoist, then Ps[qrow][key]; swizzled
    __shared__ bf16 Ks[64 * 64];   // [key][hd]; swizzled
    __shared__ bf16 Vt[64 * 64];   // [hd][key]; swizzled

    int t = threadIdx.x;           // 0..127
    int wave = t >> 6, lane = t & 63;
    int l15 = lane & 15, quad = lane >> 4;
    // bijective XCD-chunked swizzle (nwg=1024 = 8*128): same-bh q-blocks share an XCD
    int flat = blockIdx.y * gridDim.x + blockIdx.x;
    int wid = (flat & 7) * 128 + (flat >> 3);
    int q0 = (wid & 31) * 64;
    int bh = wid >> 5;
    int b = bh / NH, h = bh % NH;

    const short8 ones = (short8)0x3F80;   // bf16 1.0 splat

    float result[2][4][4] = {};           // [q-tile][n-tile][row]

    for (int phase = 0; phase < 2; ++phase) {
        const bf16* qptr = phase ? qb : qg;
        const bf16* kptr = phase ? kb : kg;
        const bf16* vtp  = phase ? vT : gvT;
        int kvlen = phase ? SEQ : PN;
        int nchunk = kvlen / 64;

        __syncthreads();   // prior phase's P reads done before Q restage
        {
            int r = t >> 1, cb = (t & 1) * 64;   // 64 rows x 128B, 64B/thread
            const bf16* qsrc = qptr + ((size_t)bh * SEQ + q0 + r) * HD + (t & 1) * 32;
            *(short8*)swzp(QPs, r, cb)      = *(const short8*)(qsrc);
            *(short8*)swzp(QPs, r, cb + 16) = *(const short8*)(qsrc + 8);
            *(short8*)swzp(QPs, r, cb + 32) = *(const short8*)(qsrc + 16);
            *(short8*)swzp(QPs, r, cb + 48) = *(const short8*)(qsrc + 24);
        }
        __syncthreads();   // Q visible
        // hoist chunk-invariant Q B-fragments (this wave's 32 q-rows)
        short8 bq[2][2];   // [q-tile][kk]
#pragma unroll
        for (int qt = 0; qt < 2; ++qt) {
            int r = wave * 32 + qt * 16 + l15;
            bq[qt][0] = *(short8*)swzp(QPs, r, quad * 16);
            bq[qt][1] = *(short8*)swzp(QPs, r, 64 + quad * 16);
        }
        // (each wave's P region == its own Q rows; no cross-wave QPs hazard)

        int sr = t >> 1, sb = (t & 1) * 64;      // staging row / byte-col (64B/thread)
        const bf16* kbase = kptr + ((size_t)bh * kvlen + sr) * HD + (t & 1) * 32;
        const bf16* vbase = vtp + (size_t)(bh * HD + sr) * kvlen + (t & 1) * 32;

        // prefetch chunk 0; advance by pointer increment
        const bf16* kn = kbase;
        const bf16* vn = vbase;
        short8 kr[4], vr[4];
#pragma unroll
        for (int j = 0; j < 4; ++j) {
            kr[j] = *(const short8*)(kn + j * 8);
            vr[j] = *(const short8*)(vn + j * 8);
        }

        f32x4 o_acc[2][4] = {};
        f32x4 l_acc[2] = {};
        for (int ch = 0; ch < nchunk; ++ch) {
            __syncthreads();   // prev chunk's Ks/Vt reads done
#pragma unroll
            for (int j = 0; j < 4; ++j) {
                *(short8*)swzp(Ks, sr, sb + j * 16) = kr[j];
                *(short8*)swzp(Vt, sr, sb + j * 16) = vr[j];
            }
            if (ch + 1 < nchunk) {     // prefetch next chunk over compute
                kn += 64 * HD;
                vn += 64;
#pragma unroll
                for (int j = 0; j < 4; ++j) {
                    kr[j] = *(const short8*)(kn + j * 8);
                    vr[j] = *(const short8*)(vn + j * 8);
                }
            }
            __syncthreads();

            // S^T = K Q^T : D[m=key (4 tiles)][n=qrow (2 tiles of 16)]
            f32x4 s_acc[2][4] = {};
#pragma unroll
            for (int kk = 0; kk < 2; ++kk) {
#pragma unroll
                for (int tn = 0; tn < 4; ++tn) {
                    short8 ak = *(short8*)swzp(Ks, tn * 16 + l15, kk * 64 + quad * 16);
                    s_acc[0][tn] = __builtin_amdgcn_mfma_f32_16x16x32_bf16(ak, bq[0][kk], s_acc[0][tn], 0, 0, 0);
                    s_acc[1][tn] = __builtin_amdgcn_mfma_f32_16x16x32_bf16(ak, bq[1][kk], s_acc[1][tn], 0, 0, 0);
                }
            }
            // P = exp2(S^T): raw v_exp + perm-pack, 8B store per (qt,tn)
#pragma unroll
            for (int qt = 0; qt < 2; ++qt)
#pragma unroll
                for (int tn = 0; tn < 4; ++tn) {
                    float e0 = __builtin_amdgcn_exp2f(s_acc[qt][tn][0]);
                    float e1 = __builtin_amdgcn_exp2f(s_acc[qt][tn][1]);
                    float e2 = __builtin_amdgcn_exp2f(s_acc[qt][tn][2]);
                    float e3 = __builtin_amdgcn_exp2f(s_acc[qt][tn][3]);
                    uint2v pw;
                    pw[0] = pk2bf(e0, e1);
                    pw[1] = pk2bf(e2, e3);
                    *(uint2v*)swzp(QPs, wave * 32 + qt * 16 + l15, tn * 32 + quad * 8) = pw;
                }
            // PV + rowsum: A = P rows, B = Vt rows (V-frags serve both q-tiles)
#pragma unroll
            for (int kk = 0; kk < 2; ++kk) {
                short8 pa0 = *(short8*)swzp(QPs, wave * 32 + l15,      kk * 64 + quad * 16);
                short8 pa1 = *(short8*)swzp(QPs, wave * 32 + 16 + l15, kk * 64 + quad * 16);
                l_acc[0] = __builtin_amdgcn_mfma_f32_16x16x32_bf16(pa0, ones, l_acc[0], 0, 0, 0);
                l_acc[1] = __builtin_amdgcn_mfma_f32_16x16x32_bf16(pa1, ones, l_acc[1], 0, 0, 0);
#pragma unroll
                for (int tn = 0; tn < 4; ++tn) {
                    short8 vb = *(short8*)swzp(Vt, tn * 16 + l15, kk * 64 + quad * 16);
                    o_acc[0][tn] = __builtin_amdgcn_mfma_f32_16x16x32_bf16(pa0, vb, o_acc[0][tn], 0, 0, 0);
                    o_acc[1][tn] = __builtin_amdgcn_mfma_f32_16x16x32_bf16(pa1, vb, o_acc[1][tn], 0, 0, 0);
                }
            }
        }
#pragma unroll
        for (int qt = 0; qt < 2; ++qt)
#pragma unroll
            for (int r = 0; r < 4; ++r) {
                float inv = 0.5f / fmaxf(l_acc[qt][r], 1e-30f);
#pragma unroll
                for (int tn = 0; tn < 4; ++tn)
                    result[qt][tn][r] += o_acc[qt][tn][r] * inv;
            }
    }

    // store attn_bf; O C-layout: col=hd(l15), row=qrow quad*4+r
#pragma unroll
    for (int qt = 0; qt < 2; ++qt)
#pragma unroll
        for (int r = 0; r < 4; ++r) {
            int srow = q0 + wave * 32 + qt * 16 + quad * 4 + r;
            int mm = srow * BSZ + b;
#pragma unroll
            for (int tn = 0; tn < 4; ++tn) {
                int dcol = h * HD + tn * 16 + l15;
                out[(size_t)mm * DIM + dcol] = f2b(result[qt][tn][r]);
            }
        }
}

// ---------------------------------------------------------------------------
extern "C" void kernel_launch(void* const* d_in, const int* in_sizes, int n_in,
                              void* d_out, int out_size, void* d_ws, size_t ws_size,
                              hipStream_t stream) {
    (void)in_sizes; (void)n_in; (void)out_size; (void)ws_size;
    const float* query = (const float*)d_in[0];
    const float* Wq_b  = (const float*)d_in[1];
    const float* bq_b  = (const float*)d_in[2];
    const float* Wk_b  = (const float*)d_in[3];
    const float* bk_b  = (const float*)d_in[4];
    const float* Wq_g  = (const float*)d_in[5];
    const float* bq_g  = (const float*)d_in[6];
    const float* Wk_g  = (const float*)d_in[7];
    const float* bk_g  = (const float*)d_in[8];
    const float* Wv    = (const float*)d_in[9];
    const float* bv    = (const float*)d_in[10];
    const float* Wo    = (const float*)d_in[11];
    const float* bo    = (const float*)d_in[12];
    float* out = (float*)d_out;

    const size_t NQ = (size_t)BSZ * NH * SEQ * HD;   // 4194304
    const size_t NP = (size_t)BSZ * NH * PN * HD;    // 524288
    bf16* qbf      = (bf16*)d_ws;                    // 4M
    bf16* wbf      = qbf + NQ;                       // 6M
    bf16* phrasebf = wbf + (size_t)6 * DIM * DIM;    // 512K
    bf16* q_b      = phrasebf + (size_t)PN * BSZ * DIM;
    bf16* k_b      = q_b + NQ;
    bf16* vT       = k_b + NQ;                       // [bh][hd][s]
    bf16* q_g      = vT + NQ;
    bf16* k_g      = q_g + NQ;                       // [bh][p][hd]
    bf16* gvT      = k_g + NP;                       // [bh][hd][p]
    bf16* attn_bf  = gvT + NP;                       // [m][dcol]
    float* bias_pack = (float*)(attn_bf + NQ);       // 6*1024 fp32

    const int QV = (SEQ * BSZ * DIM) / 8, WV6 = 6 * (DIM * DIM) / 8;
    convert_kernel<<<(QV + WV6) / 256 + 3, 256, 0, stream>>>(
        query, Wq_b, Wk_b, Wv, Wq_g, Wk_g, Wo,
        bq_b, bk_b, bv, bq_g, bk_g, bo, qbf, wbf, bias_pack);
    phrase_max_kernel<<<(PN * BSZ * DIM) / 256, 256, 0, stream>>>(query, phrasebf);

    dim3 gp((SEQ * BSZ) / 128, DIM / 128, 5);
    gemm_proj<<<gp, 256, 0, stream>>>(qbf, phrasebf, wbf, bias_pack,
                                      q_b, k_b, vT, q_g, k_g);

    gauss_v_kernel<<<BSZ * NH * HD, PN, 0, stream>>>(vT, gvT);

    dim3 g3(SEQ / 64, BSZ * NH);
    attn_kernel<<<g3, 128, 0, stream>>>(q_b, k_b, vT, q_g, k_g, gvT, attn_bf);

    dim3 gf((SEQ * BSZ) / 64, DIM / 128);
    gemm_final<<<gf, 256, 0, stream>>>(attn_bf, wbf, bias_pack, out);
}